// Round 3
// baseline (4379.001 us; speedup 1.0000x reference)
//
#include <hip/hip_runtime.h>
#include <math.h>

using u16 = unsigned short;
using u32 = unsigned int;

typedef __bf16 bf16x8 __attribute__((ext_vector_type(8)));
typedef float f32x4 __attribute__((ext_vector_type(4)));

__device__ __forceinline__ u16 f2b(float f) {
    union { float f; u32 i; } v; v.f = f;
    return (u16)((v.i + 0x7fffu + ((v.i >> 16) & 1u)) >> 16);
}
__device__ __forceinline__ float b2f(u16 u) {
    union { u32 i; float f; } v; v.i = ((u32)u) << 16; return v.f;
}
__device__ __forceinline__ float sigm(float x) { return 1.0f / (1.0f + expf(-x)); }

// =============== GEMM tile: C[64x64] = A[64xK] @ B[NxK]^T (+bias +Cin, act) ===============
// A row-major [M,K] bf16, B row-major [N,K] bf16, fp32 accum.
// Requires K % 64 == 0, M % 64 == 0. Only N may be ragged (nRem guard).
__device__ __forceinline__ void gemm_tile_body(
    const u16* __restrict__ A, int lda,
    const u16* __restrict__ B, int ldb,
    int K, int nRem,
    const float* __restrict__ bias,
    const float* __restrict__ Cin, int ldc,
    float* __restrict__ Cf, u16* __restrict__ Cb, int act)
{
    __shared__ __align__(16) u16 As[64][72];
    __shared__ __align__(16) u16 Bs[64][72];
    const int tid  = threadIdx.x;
    const int srow = tid >> 2;
    const int scol = (tid & 3) * 16;
    const int wave = tid >> 6;
    const int lane = tid & 63;
    const int lr   = lane & 15;
    const int ks   = lane >> 4;
    f32x4 acc[4] = {};
    for (int k0 = 0; k0 < K; k0 += 64) {
        const uint4* ag = (const uint4*)(A + (size_t)srow * lda + k0 + scol);
        uint4 a0 = ag[0], a1 = ag[1];
        uint4 b0, b1;
        if (nRem >= 64 || srow < nRem) {
            const uint4* bg = (const uint4*)(B + (size_t)srow * ldb + k0 + scol);
            b0 = bg[0]; b1 = bg[1];
        } else {
            b0 = make_uint4(0,0,0,0); b1 = make_uint4(0,0,0,0);
        }
        *(uint4*)&As[srow][scol]     = a0;
        *(uint4*)&As[srow][scol + 8] = a1;
        *(uint4*)&Bs[srow][scol]     = b0;
        *(uint4*)&Bs[srow][scol + 8] = b1;
        __syncthreads();
        #pragma unroll
        for (int k2 = 0; k2 < 2; ++k2) {
            bf16x8 a = *(const bf16x8*)&As[wave * 16 + lr][k2 * 32 + ks * 8];
            #pragma unroll
            for (int nf = 0; nf < 4; ++nf) {
                bf16x8 b = *(const bf16x8*)&Bs[nf * 16 + lr][k2 * 32 + ks * 8];
                acc[nf] = __builtin_amdgcn_mfma_f32_16x16x32_bf16(a, b, acc[nf], 0, 0, 0);
            }
        }
        __syncthreads();
    }
    #pragma unroll
    for (int nf = 0; nf < 4; ++nf) {
        #pragma unroll
        for (int j = 0; j < 4; ++j) {
            int r = wave * 16 + ks * 4 + j;
            int c = nf * 16 + lr;
            if (nRem < 64 && c >= nRem) continue;
            float v = acc[nf][j];
            if (bias) v += bias[c];
            if (Cin)  v += Cin[(size_t)r * ldc + c];
            if (act == 1) v = tanhf(v);
            if (Cf) Cf[(size_t)r * ldc + c] = v;
            if (Cb) Cb[(size_t)r * ldc + c] = f2b(v);
        }
    }
}

__global__ __launch_bounds__(256) void gemm_bt(
    const u16* __restrict__ A, int lda,
    const u16* __restrict__ B, int ldb,
    int N, int K,
    const float* __restrict__ bias,
    const float* __restrict__ Cin, int ldc,
    float* __restrict__ Cf, u16* __restrict__ Cb, int act)
{
    const int nT = blockIdx.x * 64;
    const int mT = blockIdx.y * 64;
    gemm_tile_body(A + (size_t)mT * lda, lda,
                   B + (size_t)nT * ldb, ldb,
                   K, N - nT,
                   bias ? bias + nT : nullptr,
                   Cin ? Cin + (size_t)mT * ldc + nT : nullptr, ldc,
                   Cf ? Cf + (size_t)mT * ldc + nT : nullptr,
                   Cb ? Cb + (size_t)mT * ldc + nT : nullptr, act);
}

// =============== Encoder recurrent step: both directions in one launch ===============
__global__ __launch_bounds__(256) void enc_step(
    const u16* __restrict__ hb,
    const u16* __restrict__ Whh_f, const u16* __restrict__ Whh_r,
    const float* __restrict__ Xf, const float* __restrict__ Xr,
    float* __restrict__ genc, int t)
{
    const int dir = blockIdx.y;
    const int nT  = blockIdx.x * 64;
    const int te  = dir ? (39 - t) : t;
    const u16*  A   = hb + dir * 64 * 512;
    const u16*  B   = (dir ? Whh_r : Whh_f) + (size_t)nT * 512;
    const float* Ci = (dir ? Xr : Xf) + (size_t)te * 64 * 2048 + nT;
    float* Cf = genc + dir * 64 * 2048 + nT;
    gemm_tile_body(A, 512, B, 512, 512, 64, nullptr, Ci, 2048, Cf, nullptr, 0);
}

__global__ void enc_pointwise(const float* __restrict__ genc, float* __restrict__ cenc,
                              u16* __restrict__ hb, u16* __restrict__ encout, int t)
{
    int i = blockIdx.x * blockDim.x + threadIdx.x;
    if (i >= 2 * 64 * 512) return;
    int dir = i >> 15, rem = i & 32767, b = rem >> 9, h = rem & 511;
    const float* g = genc + dir * 64 * 2048 + b * 2048;
    float gi = g[h], gf = g[512 + h], gg = g[1024 + h], go = g[1536 + h];
    float c  = sigm(gf) * cenc[i] + sigm(gi) * tanhf(gg);
    float hn = sigm(go) * tanhf(c);
    cenc[i] = c;
    hb[i] = f2b(hn);
    int te = dir ? (39 - t) : t;
    encout[(size_t)te * 64 * 1024 + b * 1024 + dir * 512 + h] = f2b(hn);
}

// =============== Decoder ===============
__global__ void dec_init(const float* __restrict__ h0, const float* __restrict__ c0,
                         float* __restrict__ dh, float* __restrict__ dc, u16* __restrict__ A2)
{
    int i = blockIdx.x * blockDim.x + threadIdx.x;
    if (i >= 64 * 1024) return;
    int b = i >> 10, h = i & 1023;
    dh[i] = h0[i];
    dc[i] = c0[i];
    A2[b * 2048 + 1024 + h] = f2b(h0[i]);
}

__global__ __launch_bounds__(256) void attn_kernel(
    const float* __restrict__ dh, const u16* __restrict__ matl,
    const u16* __restrict__ encout, u16* __restrict__ A1)
{
    const int b = blockIdx.x;
    const int tid = threadIdx.x;
    __shared__ float dhs[1024];
    __shared__ float sc[40];
    __shared__ float at[40];
    for (int d = tid; d < 1024; d += 256) dhs[d] = dh[b * 1024 + d];
    __syncthreads();
    const int wave = tid >> 6, lane = tid & 63;
    for (int s = wave; s < 40; s += 4) {
        const u16* ml = matl + ((size_t)s * 64 + b) * 1024 + lane * 16;
        u16 buf[16];
        *(uint4*)&buf[0] = ((const uint4*)ml)[0];
        *(uint4*)&buf[8] = ((const uint4*)ml)[1];
        float sum = 0.f;
        #pragma unroll
        for (int j = 0; j < 16; ++j) sum += b2f(buf[j]) * dhs[lane * 16 + j];
        #pragma unroll
        for (int off = 32; off; off >>= 1) sum += __shfl_xor(sum, off);
        if (lane == 0) sc[s] = sum;
    }
    __syncthreads();
    if (wave == 0) {
        float v = (lane < 40) ? sc[lane] : -1e30f;
        float m = v;
        #pragma unroll
        for (int off = 32; off; off >>= 1) m = fmaxf(m, __shfl_xor(m, off));
        float e = (lane < 40) ? expf(v - m) : 0.f;
        float s = e;
        #pragma unroll
        for (int off = 32; off; off >>= 1) s += __shfl_xor(s, off);
        if (lane < 40) at[lane] = e / s;
    }
    __syncthreads();
    {
        const int d = tid * 4;
        float s0 = 0, s1 = 0, s2 = 0, s3 = 0;
        for (int s = 0; s < 40; ++s) {
            const float a = at[s];
            const u16* eo = encout + ((size_t)s * 64 + b) * 1024 + d;
            s0 += a * b2f(eo[0]); s1 += a * b2f(eo[1]);
            s2 += a * b2f(eo[2]); s3 += a * b2f(eo[3]);
        }
        u16* o = A1 + b * 2048 + d;
        o[0] = f2b(s0); o[1] = f2b(s1); o[2] = f2b(s2); o[3] = f2b(s3);
        u16* o2 = A1 + b * 2048 + 1024 + d;
        o2[0] = f2b(dhs[d]);     o2[1] = f2b(dhs[d + 1]);
        o2[2] = f2b(dhs[d + 2]); o2[3] = f2b(dhs[d + 3]);
    }
}

__global__ void dec_pointwise(const float* __restrict__ g, float* __restrict__ dh,
                              float* __restrict__ dc, u16* __restrict__ A2,
                              u16* __restrict__ Hall, int t)
{
    int i = blockIdx.x * blockDim.x + threadIdx.x;
    if (i >= 64 * 1024) return;
    int b = i >> 10, h = i & 1023;
    const float* gr = g + b * 4096;
    float gi = gr[h], gf = gr[1024 + h], gg = gr[2048 + h], go = gr[3072 + h];
    float c  = sigm(gf) * dc[i] + sigm(gi) * tanhf(gg);
    float hn = sigm(go) * tanhf(c);
    dc[i] = c; dh[i] = hn;
    u16 hb16 = f2b(hn);
    A2[b * 2048 + 1024 + h] = hb16;
    Hall[(size_t)t * 65536 + i] = hb16;
}

__global__ __launch_bounds__(256) void logsoftmax_inplace(float* __restrict__ out)
{
    const int r = blockIdx.x;
    float* row = out + (size_t)r * 23262;
    const int tid = threadIdx.x;
    __shared__ float red[4];
    float m = -1e30f;
    for (int i = tid; i < 23262; i += 256) m = fmaxf(m, row[i]);
    #pragma unroll
    for (int off = 32; off; off >>= 1) m = fmaxf(m, __shfl_xor(m, off));
    if ((tid & 63) == 0) red[tid >> 6] = m;
    __syncthreads();
    m = fmaxf(fmaxf(red[0], red[1]), fmaxf(red[2], red[3]));
    __syncthreads();
    float s = 0.f;
    for (int i = tid; i < 23262; i += 256) s += expf(row[i] - m);
    #pragma unroll
    for (int off = 32; off; off >>= 1) s += __shfl_xor(s, off);
    if ((tid & 63) == 0) red[tid >> 6] = s;
    __syncthreads();
    s = red[0] + red[1] + red[2] + red[3];
    const float lse = m + logf(s);
    for (int i = tid; i < 23262; i += 256) row[i] = row[i] - lse;
}

// =============== Prep kernels (fp32 inputs -> bf16 staging) ===============
__global__ void gather_embed(const int* __restrict__ src_idx, const int* __restrict__ trg_idx,
                             const float* __restrict__ emb_en, const float* __restrict__ emb_de,
                             u16* __restrict__ srcp, u16* __restrict__ trgp)
{
    int z = blockIdx.y;
    int i = blockIdx.x * 256 + threadIdx.x;
    if (i >= 2560 * 320) return;
    int m = i / 320, k = i - m * 320;
    const int* idx = z ? trg_idx : src_idx;
    const float* emb = z ? emb_de : emb_en;
    u16* o = z ? trgp : srcp;
    int token = idx[m];
    o[i] = (k < 300) ? f2b(emb[(size_t)token * 300 + k]) : (u16)0;
}

__global__ void pad_w(const float* __restrict__ in, u16* __restrict__ out,
                      int R, int ldin, int colOff)
{
    int i = blockIdx.x * 256 + threadIdx.x;
    if (i >= R * 320) return;
    int r = i / 320, k = i - r * 320;
    out[i] = (k < 300) ? f2b(in[(size_t)r * ldin + colOff + k]) : (u16)0;
}

__global__ void build_wcomb(const float* __restrict__ Wih, const float* __restrict__ Whh,
                            u16* __restrict__ out)
{
    int i = blockIdx.x * 256 + threadIdx.x;
    if (i >= 4096 * 2048) return;
    int r = i >> 11, k = i & 2047;
    out[i] = f2b((k < 1024) ? Wih[(size_t)r * 1324 + k] : Whh[(size_t)r * 1024 + (k - 1024)]);
}

__global__ void transpose_wi(const float* __restrict__ Wi, u16* __restrict__ WiT)
{
    int i = blockIdx.x * 256 + threadIdx.x;
    if (i >= 1024 * 1024) return;
    int r = i >> 10, c = i & 1023;
    WiT[i] = f2b(Wi[(size_t)c * 1024 + r]);
}

// vectorized fp32 -> bf16 convert (n must be a multiple of 4)
__global__ void cvt_f32_bf16(const float* __restrict__ in, u16* __restrict__ out, int n4)
{
    int i = blockIdx.x * 256 + threadIdx.x;
    if (i >= n4) return;
    float4 v = ((const float4*)in)[i];
    ushort4 o;
    o.x = f2b(v.x); o.y = f2b(v.y); o.z = f2b(v.z); o.w = f2b(v.w);
    ((ushort4*)out)[i] = o;
}

__global__ void bias_prep(const float* __restrict__ a, const float* __restrict__ b,
                          float* __restrict__ out, int n)
{
    int i = blockIdx.x * 256 + threadIdx.x;
    if (i >= n) return;
    out[i] = a[i] + b[i];
}

// =============== Launcher ===============
extern "C" void kernel_launch(void* const* d_in, const int* in_sizes, int n_in,
                              void* d_out, int out_size, void* d_ws, size_t ws_size,
                              hipStream_t stream)
{
    const int*   src_idx = (const int*)d_in[0];
    const int*   trg_idx = (const int*)d_in[1];
    const float* d_h0    = (const float*)d_in[2];
    const float* d_c0    = (const float*)d_in[3];
    const float* emb_en  = (const float*)d_in[4];
    const float* emb_de  = (const float*)d_in[5];
    const float* W_ih_f  = (const float*)d_in[6];
    const float* W_hh_f  = (const float*)d_in[7];
    const float* b_ih_f  = (const float*)d_in[8];
    const float* b_hh_f  = (const float*)d_in[9];
    const float* W_ih_r  = (const float*)d_in[10];
    const float* W_hh_r  = (const float*)d_in[11];
    const float* b_ih_r  = (const float*)d_in[12];
    const float* b_hh_r  = (const float*)d_in[13];
    const float* W_ih_de = (const float*)d_in[14];
    const float* W_hh_de = (const float*)d_in[15];
    const float* b_ih_de = (const float*)d_in[16];
    const float* b_hh_de = (const float*)d_in[17];
    const float* W_i     = (const float*)d_in[18];
    const float* W_o     = (const float*)d_in[19];
    const float* W_gen   = (const float*)d_in[20];
    const float* b_gen   = (const float*)d_in[21];
    float* out = (float*)d_out;

    char* base = (char*)d_ws;
    size_t off = 0;
    auto alloc = [&](size_t bytes) -> void* {
        void* p = base + off;
        off = (off + bytes + 255) & ~(size_t)255;
        return p;
    };
    u16*   srcp  = (u16*)  alloc((size_t)2560 * 320 * 2);
    u16*   trgp  = (u16*)  alloc((size_t)2560 * 320 * 2);
    u16*   Wfp   = (u16*)  alloc((size_t)2048 * 320 * 2);
    u16*   Wrp   = (u16*)  alloc((size_t)2048 * 320 * 2);
    u16*   Wde   = (u16*)  alloc((size_t)4096 * 320 * 2);
    u16*   Wcomb = (u16*)  alloc((size_t)4096 * 2048 * 2);
    u16*   WiT   = (u16*)  alloc((size_t)1024 * 1024 * 2);
    u16*   Whhfb = (u16*)  alloc((size_t)2048 * 512 * 2);
    u16*   Whhrb = (u16*)  alloc((size_t)2048 * 512 * 2);
    u16*   Wob   = (u16*)  alloc((size_t)1024 * 2048 * 2);
    u16*   Wgenb = (u16*)  alloc((size_t)23262 * 1024 * 2);
    float* bef   = (float*)alloc(2048 * 4);
    float* ber   = (float*)alloc(2048 * 4);
    float* bde   = (float*)alloc(4096 * 4);
    float* Xf    = (float*)alloc((size_t)2560 * 2048 * 4);
    float* Xr    = (float*)alloc((size_t)2560 * 2048 * 4);
    float* Ede   = (float*)alloc((size_t)2560 * 4096 * 4);
    float* genc  = (float*)alloc((size_t)2 * 64 * 2048 * 4);
    u16*   hb    = (u16*)  alloc((size_t)2 * 64 * 512 * 2);
    float* cenc  = (float*)alloc((size_t)2 * 64 * 512 * 4);
    u16*   encout= (u16*)  alloc((size_t)2560 * 1024 * 2);
    u16*   matl  = (u16*)  alloc((size_t)2560 * 1024 * 2);
    float* dh    = (float*)alloc((size_t)64 * 1024 * 4);
    float* dc    = (float*)alloc((size_t)64 * 1024 * 4);
    u16*   A1    = (u16*)  alloc((size_t)64 * 2048 * 2);
    u16*   A2    = (u16*)  alloc((size_t)64 * 2048 * 2);
    float* gdec  = (float*)alloc((size_t)64 * 4096 * 4);
    u16*   Hall  = (u16*)  alloc((size_t)2560 * 1024 * 2);

    // ---- prep: fp32 -> bf16 staging (parallel) ----
    gather_embed<<<dim3(3200, 2), 256, 0, stream>>>(src_idx, trg_idx, emb_en, emb_de, srcp, trgp);
    pad_w<<<2560, 256, 0, stream>>>(W_ih_f, Wfp, 2048, 300, 0);
    pad_w<<<2560, 256, 0, stream>>>(W_ih_r, Wrp, 2048, 300, 0);
    pad_w<<<5120, 256, 0, stream>>>(W_ih_de, Wde, 4096, 1324, 1024);
    build_wcomb<<<32768, 256, 0, stream>>>(W_ih_de, W_hh_de, Wcomb);
    transpose_wi<<<4096, 256, 0, stream>>>(W_i, WiT);
    cvt_f32_bf16<<<1024, 256, 0, stream>>>(W_hh_f, Whhfb, 2048 * 512 / 4);
    cvt_f32_bf16<<<1024, 256, 0, stream>>>(W_hh_r, Whhrb, 2048 * 512 / 4);
    cvt_f32_bf16<<<2048, 256, 0, stream>>>(W_o, Wob, 1024 * 2048 / 4);
    cvt_f32_bf16<<<23262, 256, 0, stream>>>(W_gen, Wgenb, 23262 * 1024 / 4);
    bias_prep<<<8, 256, 0, stream>>>(b_ih_f, b_hh_f, bef, 2048);
    bias_prep<<<8, 256, 0, stream>>>(b_ih_r, b_hh_r, ber, 2048);
    bias_prep<<<16, 256, 0, stream>>>(b_ih_de, b_hh_de, bde, 4096);
    hipMemsetAsync(hb, 0, (size_t)2 * 64 * 512 * 2, stream);
    hipMemsetAsync(cenc, 0, (size_t)2 * 64 * 512 * 4, stream);

    // ---- input-side GEMMs (parallel over all timesteps) ----
    gemm_bt<<<dim3(32, 40), 256, 0, stream>>>(srcp, 320, Wfp, 320, 2048, 320,
                                              bef, nullptr, 2048, Xf, nullptr, 0);
    gemm_bt<<<dim3(32, 40), 256, 0, stream>>>(srcp, 320, Wrp, 320, 2048, 320,
                                              ber, nullptr, 2048, Xr, nullptr, 0);
    gemm_bt<<<dim3(64, 40), 256, 0, stream>>>(trgp, 320, Wde, 320, 4096, 320,
                                              bde, nullptr, 4096, Ede, nullptr, 0);

    // ---- encoder recurrence (both dirs per launch) ----
    for (int t = 0; t < 40; ++t) {
        enc_step<<<dim3(32, 2), 256, 0, stream>>>(hb, Whhfb, Whhrb, Xf, Xr, genc, t);
        enc_pointwise<<<256, 256, 0, stream>>>(genc, cenc, hb, encout, t);
    }

    // ---- attention precompute ----
    gemm_bt<<<dim3(16, 40), 256, 0, stream>>>(encout, 1024, WiT, 1024, 1024, 1024,
                                              nullptr, nullptr, 1024, nullptr, matl, 0);

    // ---- decoder recurrence ----
    dec_init<<<256, 256, 0, stream>>>(d_h0, d_c0, dh, dc, A2);
    for (int t = 0; t < 40; ++t) {
        attn_kernel<<<64, 256, 0, stream>>>(dh, matl, encout, A1);
        gemm_bt<<<dim3(16, 1), 256, 0, stream>>>(A1, 2048, Wob, 2048, 1024, 2048,
                                                 nullptr, nullptr, 2048, nullptr, A2, 1);
        gemm_bt<<<dim3(64, 1), 256, 0, stream>>>(A2, 2048, Wcomb, 2048, 4096, 2048,
                                                 nullptr, Ede + (size_t)t * 64 * 4096, 4096,
                                                 gdec, nullptr, 0);
        dec_pointwise<<<256, 256, 0, stream>>>(gdec, dh, dc, A2, Hall, t);
    }

    // ---- generator: one big GEMM into d_out (fp32), then in-place log_softmax ----
    gemm_bt<<<dim3(364, 40), 256, 0, stream>>>(Hall, 1024, Wgenb, 1024, 23262, 1024,
                                               b_gen, nullptr, 23262, out, nullptr, 0);
    logsoftmax_inplace<<<2560, 256, 0, stream>>>(out);
}